// Round 1
// baseline (826.459 us; speedup 1.0000x reference)
//
#include <hip/hip_runtime.h>

typedef _Float16 half8_t __attribute__((ext_vector_type(8)));
typedef _Float16 half4_t __attribute__((ext_vector_type(4)));
typedef _Float16 half2_t __attribute__((ext_vector_type(2)));
typedef float floatx4 __attribute__((ext_vector_type(4)));

__device__ __forceinline__ float sigm_f(float v) {
  return __builtin_amdgcn_rcpf(1.f + __expf(-v));
}
__device__ __forceinline__ float tanh_f(float v) {
  return 2.f * __builtin_amdgcn_rcpf(1.f + __expf(-2.f * v)) - 1.f;
}

// ---------------------------------------------------------------------------
// Weight prep: swizzle into MFMA 16x16x32 B-fragment order, f16.
// Column permutation: col n -> gate=(n>>4)&3, hcol=(n>>6)*16+(n&15),
// orig_row oc = gate*128 + hcol.  So each 64-col group = all 4 gates of one
// 16-hcol group -> wave-local LSTM cell update.
// B-frag layout: elem(kt,ntg,lane,j) = W[oc(n)][k], n=ntg*16+(lane&15),
// k = kt*32 + (lane>>4)*8 + j.  Layer1 K rows: [0,184)=w_ih, [184,192)=0,
// [192,320)=w_hh.  Layer2: [0,256)=w_ih, [256,384)=w_hh.
// ---------------------------------------------------------------------------
__global__ void prep_kernel(
    const float* __restrict__ wih1f, const float* __restrict__ whh1f,
    const float* __restrict__ bih1f, const float* __restrict__ bhh1f,
    const float* __restrict__ wih1b, const float* __restrict__ whh1b,
    const float* __restrict__ bih1b, const float* __restrict__ bhh1b,
    const float* __restrict__ wih2f, const float* __restrict__ whh2f,
    const float* __restrict__ bih2f, const float* __restrict__ bhh2f,
    const float* __restrict__ wih2b, const float* __restrict__ whh2b,
    const float* __restrict__ bih2b, const float* __restrict__ bhh2b,
    const float* __restrict__ fc1w,
    _Float16* __restrict__ wswz1, _Float16* __restrict__ wswz2,
    _Float16* __restrict__ wfc, float* __restrict__ biasc) {
  const int N1 = 327680, N2 = 393216, NF = 32768, NB = 2048;
  int idx = blockIdx.x * 256 + threadIdx.x;
  if (idx < N1) {
    int d = idx / 163840;
    int r = idx - d * 163840;
    int j = r & 7, lane = (r >> 3) & 63, ntg = (r >> 9) & 31, kt = r >> 14;
    int k = kt * 32 + (lane >> 4) * 8 + j;
    int n = ntg * 16 + (lane & 15);
    int oc = ((n >> 4) & 3) * 128 + (n >> 6) * 16 + (n & 15);
    const float* wih = d ? wih1b : wih1f;
    const float* whh = d ? whh1b : whh1f;
    float v = (k < 184) ? wih[oc * 184 + k]
                        : ((k < 192) ? 0.f : whh[oc * 128 + (k - 192)]);
    wswz1[idx] = (_Float16)v;
  } else if (idx < N1 + N2) {
    int r0 = idx - N1;
    int d = r0 / 196608;
    int r = r0 - d * 196608;
    int j = r & 7, lane = (r >> 3) & 63, ntg = (r >> 9) & 31, kt = r >> 14;
    int k = kt * 32 + (lane >> 4) * 8 + j;
    int n = ntg * 16 + (lane & 15);
    int oc = ((n >> 4) & 3) * 128 + (n >> 6) * 16 + (n & 15);
    const float* wih = d ? wih2b : wih2f;
    const float* whh = d ? whh2b : whh2f;
    float v = (k < 256) ? wih[oc * 256 + k] : whh[oc * 128 + (k - 256)];
    wswz2[r0] = (_Float16)v;
  } else if (idx < N1 + N2 + NF) {
    int r = idx - (N1 + N2);
    int j = r & 7, lane = (r >> 3) & 63, ntg = (r >> 9) & 3, kt = r >> 11;
    int k = kt * 32 + (lane >> 4) * 8 + j;
    int n = ntg * 16 + (lane & 15);  // fc1 output index, no permutation
    wfc[r] = (_Float16)fc1w[n * 512 + k];
  } else if (idx < N1 + N2 + NF + NB) {
    int r = idx - (N1 + N2 + NF);
    int n = r & 511, d = (r >> 9) & 1, l = r >> 10;
    int oc = ((n >> 4) & 3) * 128 + (n >> 6) * 16 + (n & 15);
    const float* bi = l ? (d ? bih2b : bih2f) : (d ? bih1b : bih1f);
    const float* bh = l ? (d ? bhh2b : bhh2f) : (d ? bhh1b : bhh1f);
    biasc[r] = bi[oc] + bh[oc];
  }
}

// ---------------------------------------------------------------------------
// Persistent LSTM layer (one direction per blockIdx.y).  Block = 64 batch
// rows, 512 threads = 8 waves; wave w owns cols [w*64, w*64+64) = all 4 gates
// of hidden cols [w*16, w*16+16).  gates = [x_t | h_{t-1}] @ Wswz, K=320/384,
// A staged in LDS (f16), W streamed from L2 in fragment order, acc fp32.
// ---------------------------------------------------------------------------
template <int LAYER>
__global__ __launch_bounds__(512, 2) void lstm_kernel(
    const float* __restrict__ x, const _Float16* __restrict__ hin,
    const _Float16* __restrict__ wswz, const float* __restrict__ biasc,
    _Float16* __restrict__ hout) {
  constexpr int IN = (LAYER == 1) ? 184 : 256;
  constexpr int IPAD = (LAYER == 1) ? 192 : 256;
  constexpr int KC = IPAD + 128;  // 320 / 384
  constexpr int KT = KC / 32;     // 10 / 12
  constexpr int SA = KC + 8;      // padded LDS row stride (f16 elems)

  __shared__ __align__(16) _Float16 Abuf[64 * 392];

  const int tid = threadIdx.x;
  const int wid = tid >> 6;
  const int lane = tid & 63;
  const int q = lane >> 4;
  const int l15 = lane & 15;
  const int dir = blockIdx.y;
  const int row0 = blockIdx.x << 6;

  const _Float16* __restrict__ wd = wswz + (size_t)dir * (KT * 16384);
  const float* __restrict__ bd = biasc + (dir << 9);

  float bias_frag[4];
#pragma unroll
  for (int nt = 0; nt < 4; ++nt) bias_frag[nt] = bd[(wid << 6) + (nt << 4) + l15];

  // zero pad columns + initial h section
  for (int idx = tid; idx < 64 * (KC - IN); idx += 512) {
    int r = idx / (KC - IN);
    int c = IN + (idx - r * (KC - IN));
    Abuf[r * SA + c] = (_Float16)0.f;
  }

  float c_state[4][4];
#pragma unroll
  for (int mt = 0; mt < 4; ++mt)
#pragma unroll
    for (int rg = 0; rg < 4; ++rg) c_state[mt][rg] = 0.f;

  const floatx4 fzero = {0.f, 0.f, 0.f, 0.f};

  for (int t = 0; t < 10; ++t) {
    const int t_eff = dir ? (9 - t) : t;

    // Phase A: stage x_t (layer1: fp32->f16) or h1out slice (layer2)
    if (LAYER == 1) {
      for (int idx = tid; idx < 64 * 46; idx += 512) {
        int r = idx / 46;
        int qd = idx - r * 46;
        const float4 v =
            *(const float4*)(x + (size_t)((row0 + r) * 10 + t_eff) * 184 + (qd << 2));
        half4_t hv;
        hv[0] = (_Float16)v.x; hv[1] = (_Float16)v.y;
        hv[2] = (_Float16)v.z; hv[3] = (_Float16)v.w;
        *(half4_t*)(Abuf + r * SA + (qd << 2)) = hv;
      }
    } else {
      for (int idx = tid; idx < 64 * 32; idx += 512) {
        int r = idx >> 5;
        int qd = idx & 31;
        *(uint4*)(Abuf + r * SA + (qd << 3)) =
            *(const uint4*)(hin + (size_t)((row0 + r) * 10 + t_eff) * 256 + (qd << 3));
      }
    }
    __syncthreads();  // x staged + previous step's h writes visible

    // Phase B: coalesced copy of h_{t-1} from LDS to global (overlaps GEMM)
    if (t > 0) {
      const int t_prev = dir ? (10 - t) : (t - 1);
      for (int idx = tid; idx < 64 * 16; idx += 512) {
        int r = idx >> 4;
        int cd = idx & 15;
        *(uint4*)(hout + (size_t)((row0 + r) * 10 + t_prev) * 256 + (dir << 7) + (cd << 3)) =
            *(const uint4*)(Abuf + r * SA + IPAD + (cd << 3));
      }
    }

    // Phase C: gates(64x512) = A(64xKC) @ Wswz(KCx512)
    floatx4 acc[4][4];
#pragma unroll
    for (int mt = 0; mt < 4; ++mt)
#pragma unroll
      for (int nt = 0; nt < 4; ++nt) acc[mt][nt] = fzero;

    for (int kt = 0; kt < KT; ++kt) {
      half8_t a[4];
#pragma unroll
      for (int mt = 0; mt < 4; ++mt)
        a[mt] = *(const half8_t*)(Abuf + ((mt << 4) + l15) * SA + (kt << 5) + (q << 3));
#pragma unroll
      for (int nt = 0; nt < 4; ++nt) {
        const half8_t b =
            *(const half8_t*)(wd + ((((size_t)kt << 5) + (wid << 2) + nt) * 64 + lane) * 8);
#pragma unroll
        for (int mt = 0; mt < 4; ++mt)
          acc[mt][nt] = __builtin_amdgcn_mfma_f32_16x16x32_f16(a[mt], b, acc[mt][nt], 0, 0, 0);
      }
    }
    __syncthreads();  // all reads of Abuf done before h overwrite

    // Phase E: LSTM cell, all gates wave-local (nt == gate)
#pragma unroll
    for (int mt = 0; mt < 4; ++mt) {
#pragma unroll
      for (int rg = 0; rg < 4; ++rg) {
        float ig = sigm_f(acc[mt][0][rg] + bias_frag[0]);
        float fg = sigm_f(acc[mt][1][rg] + bias_frag[1]);
        float gg = tanh_f(acc[mt][2][rg] + bias_frag[2]);
        float og = sigm_f(acc[mt][3][rg] + bias_frag[3]);
        float c = fg * c_state[mt][rg] + ig * gg;
        c_state[mt][rg] = c;
        float h = og * tanh_f(c);
        // row = mt*16 + q*4 + rg (C layout), hcol = wid*16 + l15
        Abuf[((mt << 4) + (q << 2) + rg) * SA + IPAD + (wid << 4) + l15] = (_Float16)h;
      }
    }
  }
  __syncthreads();
  {
    const int t_last = dir ? 0 : 9;
    for (int idx = tid; idx < 64 * 16; idx += 512) {
      int r = idx >> 4;
      int cd = idx & 15;
      *(uint4*)(hout + (size_t)((row0 + r) * 10 + t_last) * 256 + (dir << 7) + (cd << 3)) =
          *(const uint4*)(Abuf + r * SA + IPAD + (cd << 3));
    }
  }
}

// ---------------------------------------------------------------------------
// Maxpool (groups of 5 over T) + FC 512->64 relu -> 64->1.  One block = 64
// samples; pooled staged f16 in LDS, fc1 via MFMA, fc2 via shfl reduce.
// pooled flat index p = f*2 + g  (f feature 0..255+dir, g time-group).
// ---------------------------------------------------------------------------
__global__ __launch_bounds__(256) void fc_kernel(
    const _Float16* __restrict__ h2, const _Float16* __restrict__ wfc,
    const float* __restrict__ fc1b, const float* __restrict__ fc2w,
    const float* __restrict__ fc2b, float* __restrict__ out) {
  __shared__ __align__(16) _Float16 pooled[64 * 520];
  const int tid = threadIdx.x;
  const int s0 = blockIdx.x << 6;

  for (int idx = tid; idx < 64 * 128; idx += 256) {
    int s = idx >> 7;
    int part = idx & 127;  // covers features part*2, part*2+1
    const _Float16* base = h2 + (size_t)(s0 + s) * 10 * 256 + (part << 1);
    float m00 = -3.4e38f, m01 = -3.4e38f, m10 = -3.4e38f, m11 = -3.4e38f;
#pragma unroll
    for (int t = 0; t < 10; ++t) {
      half2_t hv = *(const half2_t*)(base + t * 256);
      float f0 = (float)hv[0], f1 = (float)hv[1];
      if (t < 5) { m00 = fmaxf(m00, f0); m10 = fmaxf(m10, f1); }
      else       { m01 = fmaxf(m01, f0); m11 = fmaxf(m11, f1); }
    }
    half4_t pv;
    pv[0] = (_Float16)m00; pv[1] = (_Float16)m01;
    pv[2] = (_Float16)m10; pv[3] = (_Float16)m11;
    *(half4_t*)(pooled + s * 520 + (part << 2)) = pv;
  }
  __syncthreads();

  const int wid = tid >> 6, lane = tid & 63, q = lane >> 4, l15 = lane & 15;
  const int m0 = wid << 4;  // this wave's 16 samples

  const floatx4 fzero = {0.f, 0.f, 0.f, 0.f};
  floatx4 acc[4];
#pragma unroll
  for (int nt = 0; nt < 4; ++nt) acc[nt] = fzero;

#pragma unroll
  for (int kt = 0; kt < 16; ++kt) {
    half8_t a = *(const half8_t*)(pooled + (m0 + l15) * 520 + (kt << 5) + (q << 3));
#pragma unroll
    for (int nt = 0; nt < 4; ++nt) {
      half8_t b = *(const half8_t*)(wfc + ((((size_t)kt << 2) + nt) * 64 + lane) * 8);
      acc[nt] = __builtin_amdgcn_mfma_f32_16x16x32_f16(a, b, acc[nt], 0, 0, 0);
    }
  }

  float b1[4], w2[4];
#pragma unroll
  for (int nt = 0; nt < 4; ++nt) {
    b1[nt] = fc1b[(nt << 4) + l15];
    w2[nt] = fc2w[(nt << 4) + l15];
  }
  const float c2b = fc2b[0];

#pragma unroll
  for (int rg = 0; rg < 4; ++rg) {
    float v = 0.f;
#pragma unroll
    for (int nt = 0; nt < 4; ++nt)
      v += fmaxf(acc[nt][rg] + b1[nt], 0.f) * w2[nt];
    v += __shfl_xor(v, 1, 64);
    v += __shfl_xor(v, 2, 64);
    v += __shfl_xor(v, 4, 64);
    v += __shfl_xor(v, 8, 64);
    if (l15 == 0) out[s0 + m0 + (q << 2) + rg] = v + c2b;  // row = q*4+rg
  }
}

// ---------------------------------------------------------------------------
extern "C" void kernel_launch(void* const* d_in, const int* in_sizes, int n_in,
                              void* d_out, int out_size, void* d_ws, size_t ws_size,
                              hipStream_t stream) {
  const float* x     = (const float*)d_in[0];
  const float* wih1f = (const float*)d_in[1];
  const float* whh1f = (const float*)d_in[2];
  const float* bih1f = (const float*)d_in[3];
  const float* bhh1f = (const float*)d_in[4];
  const float* wih1b = (const float*)d_in[5];
  const float* whh1b = (const float*)d_in[6];
  const float* bih1b = (const float*)d_in[7];
  const float* bhh1b = (const float*)d_in[8];
  const float* wih2f = (const float*)d_in[9];
  const float* whh2f = (const float*)d_in[10];
  const float* bih2f = (const float*)d_in[11];
  const float* bhh2f = (const float*)d_in[12];
  const float* wih2b = (const float*)d_in[13];
  const float* whh2b = (const float*)d_in[14];
  const float* bih2b = (const float*)d_in[15];
  const float* bhh2b = (const float*)d_in[16];
  const float* fc1w  = (const float*)d_in[17];
  const float* fc1b  = (const float*)d_in[18];
  const float* fc2w  = (const float*)d_in[19];
  const float* fc2b  = (const float*)d_in[20];
  float* out = (float*)d_out;

  // workspace layout (all offsets 16B-aligned)
  if (ws_size < (size_t)169287680) return;
  _Float16* h1out = (_Float16*)d_ws;            // 16384*10*256 f16
  _Float16* h2out = h1out + (size_t)41943040;   // 16384*10*256 f16
  _Float16* wswz1 = h2out + (size_t)41943040;   // 2*10*32*64*8
  _Float16* wswz2 = wswz1 + 327680;             // 2*12*32*64*8
  _Float16* wfc   = wswz2 + 393216;             // 16*4*64*8
  float* biasc    = (float*)(wfc + 32768);      // 2 layers * 2 dirs * 512 f32

  prep_kernel<<<2952, 256, 0, stream>>>(
      wih1f, whh1f, bih1f, bhh1f, wih1b, whh1b, bih1b, bhh1b,
      wih2f, whh2f, bih2f, bhh2f, wih2b, whh2b, bih2b, bhh2b, fc1w,
      wswz1, wswz2, wfc, biasc);
  lstm_kernel<1><<<dim3(256, 2), 512, 0, stream>>>(x, nullptr, wswz1, biasc, h1out);
  lstm_kernel<2><<<dim3(256, 2), 512, 0, stream>>>(nullptr, h1out, wswz2, biasc + 1024, h2out);
  fc_kernel<<<256, 256, 0, stream>>>(h2out, wfc, fc1b, fc2w, fc2b, out);
}